// Round 1
// baseline (56972.516 us; speedup 1.0000x reference)
//
#include <hip/hip_runtime.h>
#include <stddef.h>
#include <math.h>

static constexpr int B = 64, P = 196, ED = 2048, AD = 512, DD = 512, E = 300, V = 1000, T = 96, TD = 95;

// d_out layout (all float32), outputs concatenated flat in return order:
// predictions (B,TD,V), caps (B,T), decode_lengths (B), alphas (B,TD,P), sort_ind (B)
static constexpr size_t POFF   = 0;
static constexpr size_t CAPOFF = (size_t)B * TD * V;          // 6,080,000
static constexpr size_t DLOFF  = CAPOFF + (size_t)B * T;      // 6,086,144
static constexpr size_t AOFF   = DLOFF + B;                   // 6,086,208
static constexpr size_t SOFF   = AOFF + (size_t)B * TD * P;   // 7,276,688

__device__ __forceinline__ float sigm(float x) { return 1.0f / (1.0f + expf(-x)); }

// ---------------------------------------------------------------------------
// K0: stable descending sort by length + gather caps + write int-ish outputs
// ---------------------------------------------------------------------------
__global__ __launch_bounds__(64) void k_sort(const int* __restrict__ lens,
                                             const int* __restrict__ caps_in,
                                             int* __restrict__ sidx,
                                             int* __restrict__ dlen,
                                             int* __restrict__ caps_s,
                                             float* __restrict__ out) {
    __shared__ int sl[B];
    __shared__ int ss[B];
    int i = threadIdx.x;
    sl[i] = lens[i];
    __syncthreads();
    int li = sl[i];
    int r = 0;
    for (int j = 0; j < B; j++) {
        int lj = sl[j];
        r += (lj > li) || (lj == li && j < i);
    }
    ss[r] = i;
    sidx[r] = i;
    dlen[r] = li - 1;
    out[DLOFF + r] = (float)(li - 1);
    out[SOFF + r] = (float)i;
    __syncthreads();
    for (int idx = i; idx < B * T; idx += B) {
        int b = idx / T, tt = idx % T;
        int v = caps_in[ss[b] * T + tt];
        caps_s[idx] = v;
        out[CAPOFF + idx] = (float)v;
    }
}

// ---------------------------------------------------------------------------
// K1: mean over P of sorted encoder_out -> mean_eo (B, ED)
// ---------------------------------------------------------------------------
__global__ __launch_bounds__(256) void k_mean(const float* __restrict__ eo,
                                              const int* __restrict__ sidx,
                                              float* __restrict__ mean_eo) {
    int b = blockIdx.y;
    int d = blockIdx.x * 256 + threadIdx.x;
    const float* base = eo + ((size_t)sidx[b] * P) * ED + d;
    float s = 0.f;
    for (int p = 0; p < P; p++) s += base[(size_t)p * ED];
    mean_eo[(size_t)b * ED + d] = s * (1.0f / (float)P);
}

// ---------------------------------------------------------------------------
// K2: h0 = mean_eo @ W_init_h + b ; c0 likewise. thread per (b,j)
// ---------------------------------------------------------------------------
__global__ __launch_bounds__(256) void k_init(const float* __restrict__ mean_eo,
                                              const float* __restrict__ Wh, const float* __restrict__ bh,
                                              const float* __restrict__ Wc, const float* __restrict__ bc,
                                              float* __restrict__ h, float* __restrict__ c) {
    int idx = blockIdx.x * 256 + threadIdx.x;  // B*DD
    int b = idx >> 9, j = idx & 511;
    const float* m = mean_eo + (size_t)b * ED;
    float ah = bh[j], ac = bc[j];
    for (int k = 0; k < ED; k++) {
        float mv = m[k];
        ah += mv * Wh[(size_t)k * DD + j];
        ac += mv * Wc[(size_t)k * DD + j];
    }
    h[idx] = ah;
    c[idx] = ac;
}

// ---------------------------------------------------------------------------
// K3: att1[m, n] = eo_sorted[m, :] @ W_enc_att[:, n] + b_enc_att[n]
//     m = b*P + p (12544), n in [0,512), K = 2048.  64x64 tile, 4x4/thread.
// ---------------------------------------------------------------------------
__global__ __launch_bounds__(256) void k_att1(const float* __restrict__ eo,
                                              const float* __restrict__ W,
                                              const float* __restrict__ bias,
                                              const int* __restrict__ sidx,
                                              float* __restrict__ att1) {
    int m0 = blockIdx.x * 64, n0 = blockIdx.y * 64;
    __shared__ float sA[16][68];
    __shared__ float sB[16][68];
    int tid = threadIdx.x;
    int tx = tid & 15, ty = tid >> 4;
    float acc[4][4] = {};

    int la_m = tid >> 2;        // 0..63
    int la_k = (tid & 3) * 4;   // 0,4,8,12
    int lb_k = tid >> 4;        // 0..15
    int lb_n = (tid & 15) * 4;  // 0..60

    int mA = m0 + la_m;
    int bA = mA / P, pA = mA % P;
    const float* arow = eo + ((size_t)sidx[bA] * P + pA) * ED;

    for (int k0 = 0; k0 < ED; k0 += 16) {
        float4 av = *(const float4*)(arow + k0 + la_k);
        sA[la_k + 0][la_m] = av.x;
        sA[la_k + 1][la_m] = av.y;
        sA[la_k + 2][la_m] = av.z;
        sA[la_k + 3][la_m] = av.w;
        float4 bv = *(const float4*)(W + (size_t)(k0 + lb_k) * AD + n0 + lb_n);
        *(float4*)&sB[lb_k][lb_n] = bv;
        __syncthreads();
#pragma unroll
        for (int kk = 0; kk < 16; kk++) {
            float4 a4 = *(const float4*)&sA[kk][ty * 4];
            float4 b4 = *(const float4*)&sB[kk][tx * 4];
            float av_[4] = {a4.x, a4.y, a4.z, a4.w};
            float bv_[4] = {b4.x, b4.y, b4.z, b4.w};
#pragma unroll
            for (int i = 0; i < 4; i++)
#pragma unroll
                for (int j = 0; j < 4; j++) acc[i][j] += av_[i] * bv_[j];
        }
        __syncthreads();
    }
#pragma unroll
    for (int i = 0; i < 4; i++) {
        int m = m0 + ty * 4 + i;
        int n = n0 + tx * 4;
        float4 o;
        o.x = acc[i][0] + bias[n + 0];
        o.y = acc[i][1] + bias[n + 1];
        o.z = acc[i][2] + bias[n + 2];
        o.w = acc[i][3] + bias[n + 3];
        *(float4*)(att1 + (size_t)m * AD + n) = o;
    }
}

// ---------------------------------------------------------------------------
// S1: per-b block: att2 = h@W_dec_att + b ; e = relu(att1+att2)·w_full + b_full
//     softmax over P -> alpha (ws, unmasked) + alphas output (masked)
// ---------------------------------------------------------------------------
__global__ __launch_bounds__(256) void k_attsoft(const float* __restrict__ h,
                                                 const float* __restrict__ att1,
                                                 const float* __restrict__ Wd,
                                                 const float* __restrict__ bd,
                                                 const float* __restrict__ wf,
                                                 const float* __restrict__ bf,
                                                 const int* __restrict__ dlen,
                                                 float* __restrict__ alpha,
                                                 float* __restrict__ out, int t) {
    int b = blockIdx.x;
    int tid = threadIdx.x;
    __shared__ float sh[AD];
    __shared__ float sa2[AD];
    __shared__ float swf[AD];
    __shared__ float se[224];
    __shared__ float red[256];

    sh[tid] = h[(size_t)b * DD + tid];
    sh[tid + 256] = h[(size_t)b * DD + tid + 256];
    swf[tid] = wf[tid];
    swf[tid + 256] = wf[tid + 256];
    __syncthreads();

    for (int a = tid; a < AD; a += 256) {
        float acc = bd[a];
        for (int k = 0; k < DD; k++) acc += sh[k] * Wd[(size_t)k * AD + a];
        sa2[a] = acc;
    }
    __syncthreads();

    if (tid < P) {
        const float* row = att1 + ((size_t)b * P + tid) * AD;
        float acc = bf[0];
        for (int a = 0; a < AD; a++) {
            float v = row[a] + sa2[a];
            acc += fmaxf(v, 0.f) * swf[a];
        }
        se[tid] = acc;
    }
    __syncthreads();

    // softmax over P
    red[tid] = (tid < P) ? se[tid] : -1e30f;
    __syncthreads();
    for (int s = 128; s > 0; s >>= 1) {
        if (tid < s) red[tid] = fmaxf(red[tid], red[tid + s]);
        __syncthreads();
    }
    float mx = red[0];
    __syncthreads();
    float ex = (tid < P) ? expf(se[tid] - mx) : 0.f;
    red[tid] = ex;
    __syncthreads();
    for (int s = 128; s > 0; s >>= 1) {
        if (tid < s) red[tid] += red[tid + s];
        __syncthreads();
    }
    float inv = 1.0f / red[0];
    if (tid < P) {
        float a = ex * inv;
        alpha[(size_t)b * P + tid] = a;
        float m = (dlen[b] > t) ? 1.f : 0.f;
        out[AOFF + ((size_t)b * TD + t) * P + tid] = a * m;
    }
}

// ---------------------------------------------------------------------------
// S2: awe[b,d] = sum_p eo_sorted[b,p,d] * alpha[b,p]
// ---------------------------------------------------------------------------
__global__ __launch_bounds__(256) void k_awe(const float* __restrict__ eo,
                                             const int* __restrict__ sidx,
                                             const float* __restrict__ alpha,
                                             float* __restrict__ awe) {
    int b = blockIdx.y;
    int d = blockIdx.x * 256 + threadIdx.x;
    __shared__ float sal[P];
    if (threadIdx.x < P) sal[threadIdx.x] = alpha[(size_t)b * P + threadIdx.x];
    __syncthreads();
    const float* base = eo + ((size_t)sidx[b] * P) * ED + d;
    float acc = 0.f;
    for (int p = 0; p < P; p++) acc += base[(size_t)p * ED] * sal[p];
    awe[(size_t)b * ED + d] = acc;
}

// ---------------------------------------------------------------------------
// S3: xg[b,j] = sigmoid(h@W_fbeta + b_fbeta)[b,j] * awe[b,j]
// ---------------------------------------------------------------------------
__global__ __launch_bounds__(256) void k_xg(const float* __restrict__ h,
                                            const float* __restrict__ Wfb,
                                            const float* __restrict__ bfb,
                                            const float* __restrict__ awe,
                                            float* __restrict__ xg) {
    int idx = blockIdx.x * 256 + threadIdx.x;  // B*ED
    int b = idx >> 11, j = idx & 2047;
    const float* hr = h + (size_t)b * DD;
    float acc = bfb[j];
    for (int k = 0; k < DD; k++) acc += hr[k] * Wfb[(size_t)k * ED + j];
    xg[idx] = sigm(acc) * awe[idx];
}

// ---------------------------------------------------------------------------
// S4: gates = [emb_t, xg, h] @ [W_ih ; W_hh] + b_ih + b_hh
//     M=64(b), N=2048, K=2860.  BM=64 BN=32 BK=32, 8 outputs/thread.
// ---------------------------------------------------------------------------
__global__ __launch_bounds__(256) void k_gates(const float* __restrict__ xg,
                                               const float* __restrict__ h,
                                               const float* __restrict__ emb,
                                               const int* __restrict__ caps_s,
                                               const float* __restrict__ Wih,
                                               const float* __restrict__ Whh,
                                               const float* __restrict__ bih,
                                               const float* __restrict__ bhh,
                                               float* __restrict__ gates, int t) {
    constexpr int K = E + ED + DD;  // 2860
    int n0 = blockIdx.x * 32;
    __shared__ float sX[32][65];
    __shared__ float sW[32][33];
    int tid = threadIdx.x;
    int tb = tid & 15, tj = tid >> 4;
    float acc[4][2] = {};

    for (int k0 = 0; k0 < K; k0 += 32) {
#pragma unroll
        for (int i = 0; i < 8; i++) {
            int l = tid + i * 256;
            int b = l >> 5, kk = l & 31;
            int kg = k0 + kk;
            float v = 0.f;
            if (kg < E) v = emb[(size_t)caps_s[b * T + t] * E + kg];
            else if (kg < E + ED) v = xg[(size_t)b * ED + (kg - E)];
            else if (kg < K) v = h[(size_t)b * DD + (kg - E - ED)];
            sX[kk][b] = v;
        }
#pragma unroll
        for (int i = 0; i < 4; i++) {
            int l = tid + i * 256;
            int kk = l >> 5, nn = l & 31;
            int kg = k0 + kk;
            float w = 0.f;
            if (kg < E + ED) w = Wih[(size_t)kg * (4 * DD) + n0 + nn];
            else if (kg < K) w = Whh[(size_t)(kg - E - ED) * (4 * DD) + n0 + nn];
            sW[kk][nn] = w;
        }
        __syncthreads();
#pragma unroll
        for (int kk = 0; kk < 32; kk++) {
            float w0 = sW[kk][tj * 2 + 0];
            float w1 = sW[kk][tj * 2 + 1];
#pragma unroll
            for (int i = 0; i < 4; i++) {
                float a = sX[kk][tb * 4 + i];
                acc[i][0] += a * w0;
                acc[i][1] += a * w1;
            }
        }
        __syncthreads();
    }
#pragma unroll
    for (int i = 0; i < 4; i++)
#pragma unroll
        for (int j = 0; j < 2; j++) {
            int b = tb * 4 + i, n = n0 + tj * 2 + j;
            gates[(size_t)b * (4 * DD) + n] = acc[i][j] + bih[n] + bhh[n];
        }
}

// ---------------------------------------------------------------------------
// S5: LSTM cell + mask blend
// ---------------------------------------------------------------------------
__global__ __launch_bounds__(256) void k_cell(const float* __restrict__ gates,
                                              const float* __restrict__ hc,
                                              const float* __restrict__ cc,
                                              const int* __restrict__ dlen,
                                              float* __restrict__ hn,
                                              float* __restrict__ cn, int t) {
    int idx = blockIdx.x * 256 + threadIdx.x;  // B*DD
    int b = idx >> 9, j = idx & 511;
    const float* g = gates + (size_t)b * (4 * DD);
    float gi = g[j], gf = g[DD + j], gg = g[2 * DD + j], go = g[3 * DD + j];
    float cold = cc[idx], hold = hc[idx];
    float cnew = sigm(gf) * cold + sigm(gi) * tanhf(gg);
    float hnew = sigm(go) * tanhf(cnew);
    bool m = dlen[b] > t;
    hn[idx] = m ? hnew : hold;
    cn[idx] = m ? cnew : cold;
}

// ---------------------------------------------------------------------------
// S6: preds = (h2 @ W_fc + b_fc) * mb  -> d_out predictions slice
// ---------------------------------------------------------------------------
__global__ __launch_bounds__(256) void k_preds(const float* __restrict__ h,
                                               const float* __restrict__ Wfc,
                                               const float* __restrict__ bfc,
                                               const int* __restrict__ dlen,
                                               float* __restrict__ out, int t) {
    int idx = blockIdx.x * 256 + threadIdx.x;
    if (idx >= B * V) return;
    int b = idx / V, v = idx % V;
    const float* hr = h + (size_t)b * DD;
    float acc = bfc[v];
    for (int k = 0; k < DD; k++) acc += hr[k] * Wfc[(size_t)k * V + v];
    bool m = dlen[b] > t;
    out[POFF + ((size_t)b * TD + t) * V + v] = m ? acc : 0.f;
}

// ---------------------------------------------------------------------------
extern "C" void kernel_launch(void* const* d_in, const int* in_sizes, int n_in,
                              void* d_out, int out_size, void* d_ws, size_t ws_size,
                              hipStream_t stream) {
    const float* eo    = (const float*)d_in[0];
    const int*   caps  = (const int*)d_in[1];
    const int*   lens  = (const int*)d_in[2];
    const float* emb   = (const float*)d_in[3];
    const float* Wea   = (const float*)d_in[4];
    const float* bea   = (const float*)d_in[5];
    const float* Wda   = (const float*)d_in[6];
    const float* bda   = (const float*)d_in[7];
    const float* wfull = (const float*)d_in[8];
    const float* bfull = (const float*)d_in[9];
    const float* Wih_  = (const float*)d_in[10];
    const float* bih_  = (const float*)d_in[11];
    const float* Wic   = (const float*)d_in[12];
    const float* bic   = (const float*)d_in[13];
    const float* Wfb   = (const float*)d_in[14];
    const float* bfb   = (const float*)d_in[15];
    const float* Wih   = (const float*)d_in[16];
    const float* bih   = (const float*)d_in[17];
    const float* Whh   = (const float*)d_in[18];
    const float* bhh   = (const float*)d_in[19];
    const float* Wfc   = (const float*)d_in[20];
    const float* bfc   = (const float*)d_in[21];
    float* out = (float*)d_out;

    char* w = (char*)d_ws;
    auto carve = [&](size_t bytes) -> void* {
        void* p = (void*)w;
        w += (bytes + 255) & ~(size_t)255;
        return p;
    };
    int* sidx    = (int*)carve(B * 4);
    int* dlen    = (int*)carve(B * 4);
    int* caps_s  = (int*)carve((size_t)B * T * 4);
    float* mean_eo = (float*)carve((size_t)B * ED * 4);
    float* hb0   = (float*)carve((size_t)B * DD * 4);
    float* hb1   = (float*)carve((size_t)B * DD * 4);
    float* cb0   = (float*)carve((size_t)B * DD * 4);
    float* cb1   = (float*)carve((size_t)B * DD * 4);
    float* att1  = (float*)carve((size_t)B * P * AD * 4);
    float* alpha = (float*)carve((size_t)B * P * 4);
    float* awe   = (float*)carve((size_t)B * ED * 4);
    float* xg    = (float*)carve((size_t)B * ED * 4);
    float* gates = (float*)carve((size_t)B * 4 * DD * 4);
    float* hb[2] = {hb0, hb1};
    float* cb[2] = {cb0, cb1};

    k_sort<<<1, 64, 0, stream>>>(lens, caps, sidx, dlen, caps_s, out);
    k_mean<<<dim3(ED / 256, B), 256, 0, stream>>>(eo, sidx, mean_eo);
    k_init<<<(B * DD) / 256, 256, 0, stream>>>(mean_eo, Wih_, bih_, Wic, bic, hb[0], cb[0]);
    k_att1<<<dim3((B * P) / 64, AD / 64), 256, 0, stream>>>(eo, Wea, bea, sidx, att1);

    for (int t = 0; t < TD; t++) {
        float* hc = hb[t & 1];
        float* cc = cb[t & 1];
        float* hn = hb[(t + 1) & 1];
        float* cn = cb[(t + 1) & 1];
        k_attsoft<<<B, 256, 0, stream>>>(hc, att1, Wda, bda, wfull, bfull, dlen, alpha, out, t);
        k_awe<<<dim3(ED / 256, B), 256, 0, stream>>>(eo, sidx, alpha, awe);
        k_xg<<<(B * ED) / 256, 256, 0, stream>>>(hc, Wfb, bfb, awe, xg);
        k_gates<<<(4 * DD) / 32, 256, 0, stream>>>(xg, hc, emb, caps_s, Wih, Whh, bih, bhh, gates, t);
        k_cell<<<(B * DD) / 256, 256, 0, stream>>>(gates, hc, cc, dlen, hn, cn, t);
        k_preds<<<(B * V + 255) / 256, 256, 0, stream>>>(hn, Wfc, bfc, dlen, out, t);
    }
}

// Round 2
// 20611.948 us; speedup vs baseline: 2.7641x; 2.7641x over previous
//
#include <hip/hip_runtime.h>
#include <stddef.h>
#include <math.h>

static constexpr int B = 64, P = 196, ED = 2048, AD = 512, DD = 512, E = 300, V = 1000, T = 96, TD = 95;
static constexpr int KX = E + ED;      // 2348: [emb | xg] rows of x
static constexpr int KTOT = KX + DD;   // 2860: + h rows
static constexpr int KSPLIT = 8;
static constexpr int KPER = 368;       // 23 tiles of 16; 8*368 = 2944 >= 2860
static constexpr int NG = 4 * DD;      // 2048

// d_out layout (all float32): predictions (B,TD,V), caps (B,T), decode_lengths (B),
// alphas (B,TD,P), sort_ind (B)
static constexpr size_t POFF   = 0;
static constexpr size_t CAPOFF = (size_t)B * TD * V;
static constexpr size_t DLOFF  = CAPOFF + (size_t)B * T;
static constexpr size_t AOFF   = DLOFF + B;
static constexpr size_t SOFF   = AOFF + (size_t)B * TD * P;

__device__ __forceinline__ float sigm(float x) { return 1.0f / (1.0f + expf(-x)); }

// ---------------------------------------------------------------------------
// K0: stable descending sort by length + gather caps + write int-ish outputs
// ---------------------------------------------------------------------------
__global__ __launch_bounds__(64) void k_sort(const int* __restrict__ lens,
                                             const int* __restrict__ caps_in,
                                             int* __restrict__ sidx,
                                             int* __restrict__ dlen,
                                             int* __restrict__ caps_s,
                                             float* __restrict__ out) {
    __shared__ int sl[B];
    __shared__ int ss[B];
    int i = threadIdx.x;
    sl[i] = lens[i];
    __syncthreads();
    int li = sl[i];
    int r = 0;
    for (int j = 0; j < B; j++) {
        int lj = sl[j];
        r += (lj > li) || (lj == li && j < i);
    }
    ss[r] = i;
    sidx[r] = i;
    dlen[r] = li - 1;
    out[DLOFF + r] = (float)(li - 1);
    out[SOFF + r] = (float)i;
    __syncthreads();
    for (int idx = i; idx < B * T; idx += B) {
        int b = idx / T, tt = idx % T;
        int v = caps_in[ss[b] * T + tt];
        caps_s[idx] = v;
        out[CAPOFF + idx] = (float)v;
    }
}

// ---------------------------------------------------------------------------
// K1: mean over P of sorted encoder_out -> mean_eo (B, ED)
// ---------------------------------------------------------------------------
__global__ __launch_bounds__(256) void k_mean(const float* __restrict__ eo,
                                              const int* __restrict__ sidx,
                                              float* __restrict__ mean_eo) {
    int b = blockIdx.y;
    int d = blockIdx.x * 256 + threadIdx.x;
    const float* base = eo + ((size_t)sidx[b] * P) * ED + d;
    float s = 0.f;
    for (int p = 0; p < P; p++) s += base[(size_t)p * ED];
    mean_eo[(size_t)b * ED + d] = s * (1.0f / (float)P);
}

// ---------------------------------------------------------------------------
// K2: h0/c0 init; also seeds the h-rows of xT (K-major x buffer)
// ---------------------------------------------------------------------------
__global__ __launch_bounds__(256) void k_init(const float* __restrict__ mean_eo,
                                              const float* __restrict__ Wh, const float* __restrict__ bh,
                                              const float* __restrict__ Wc, const float* __restrict__ bc,
                                              float* __restrict__ h, float* __restrict__ c,
                                              float* __restrict__ xT) {
    int idx = blockIdx.x * 256 + threadIdx.x;  // B*DD
    int b = idx >> 9, j = idx & 511;
    const float* m = mean_eo + (size_t)b * ED;
    float ah = bh[j], ac = bc[j];
    for (int k = 0; k < ED; k++) {
        float mv = m[k];
        ah += mv * Wh[(size_t)k * DD + j];
        ac += mv * Wc[(size_t)k * DD + j];
    }
    h[idx] = ah;
    c[idx] = ac;
    xT[(size_t)(KX + j) * B + b] = ah;
}

// ---------------------------------------------------------------------------
// K3: att1[m,n] = eo_sorted[m,:] @ W_enc_att[:,n] + b   (row-major, B*P x AD)
// ---------------------------------------------------------------------------
__global__ __launch_bounds__(256) void k_att1(const float* __restrict__ eo,
                                              const float* __restrict__ W,
                                              const float* __restrict__ bias,
                                              const int* __restrict__ sidx,
                                              float* __restrict__ att1) {
    int m0 = blockIdx.x * 64, n0 = blockIdx.y * 64;
    __shared__ float sA[16][68];
    __shared__ float sB[16][68];
    int tid = threadIdx.x;
    int tx = tid & 15, ty = tid >> 4;
    float acc[4][4] = {};

    int la_m = tid >> 2;
    int la_k = (tid & 3) * 4;
    int lb_k = tid >> 4;
    int lb_n = (tid & 15) * 4;

    int mA = m0 + la_m;
    int bA = mA / P, pA = mA % P;
    const float* arow = eo + ((size_t)sidx[bA] * P + pA) * ED;

    for (int k0 = 0; k0 < ED; k0 += 16) {
        float4 av = *(const float4*)(arow + k0 + la_k);
        sA[la_k + 0][la_m] = av.x;
        sA[la_k + 1][la_m] = av.y;
        sA[la_k + 2][la_m] = av.z;
        sA[la_k + 3][la_m] = av.w;
        float4 bv = *(const float4*)(W + (size_t)(k0 + lb_k) * AD + n0 + lb_n);
        *(float4*)&sB[lb_k][lb_n] = bv;
        __syncthreads();
#pragma unroll
        for (int kk = 0; kk < 16; kk++) {
            float4 a4 = *(const float4*)&sA[kk][ty * 4];
            float4 b4 = *(const float4*)&sB[kk][tx * 4];
            float av_[4] = {a4.x, a4.y, a4.z, a4.w};
            float bv_[4] = {b4.x, b4.y, b4.z, b4.w};
#pragma unroll
            for (int i = 0; i < 4; i++)
#pragma unroll
                for (int j = 0; j < 4; j++) acc[i][j] += av_[i] * bv_[j];
        }
        __syncthreads();
    }
#pragma unroll
    for (int i = 0; i < 4; i++) {
        int m = m0 + ty * 4 + i;
        int n = n0 + tx * 4;
        float4 o;
        o.x = acc[i][0] + bias[n + 0];
        o.y = acc[i][1] + bias[n + 1];
        o.z = acc[i][2] + bias[n + 2];
        o.w = acc[i][3] + bias[n + 3];
        *(float4*)(att1 + (size_t)m * AD + n) = o;
    }
}

// ---------------------------------------------------------------------------
// S_A: blocks [0,npred): preds for step t from h2.
//      blocks [npred, npred+64): attention+softmax for step t+1 from same h2.
// ---------------------------------------------------------------------------
__global__ __launch_bounds__(256) void k_attpred(const float* __restrict__ h,
                                                 const float* __restrict__ att1,
                                                 const float* __restrict__ Wd,
                                                 const float* __restrict__ bd,
                                                 const float* __restrict__ wf,
                                                 const float* __restrict__ bfv,
                                                 const float* __restrict__ Wfc,
                                                 const float* __restrict__ bfc,
                                                 const int* __restrict__ dlen,
                                                 float* __restrict__ alpha,
                                                 float* __restrict__ out,
                                                 int t, int npred) {
    int bid = blockIdx.x;
    int tid = threadIdx.x;
    if (bid < npred) {
        int idx = bid * 256 + tid;
        if (idx < B * V) {
            int b = idx / V, v = idx - b * V;
            const float* hr = h + (size_t)b * DD;
            float acc = bfc[v];
            for (int k = 0; k < DD; k++) acc += hr[k] * Wfc[(size_t)k * V + v];
            bool m = dlen[b] > t;
            out[POFF + ((size_t)b * TD + t) * V + v] = m ? acc : 0.f;
        }
        return;
    }
    int t1 = t + 1;
    if (t1 >= TD) return;
    int b = bid - npred;
    __shared__ float shh[DD];
    __shared__ float sa2[AD];
    __shared__ float swf[AD];
    __shared__ float se[P];
    __shared__ float red[256];

    shh[tid] = h[(size_t)b * DD + tid];
    shh[tid + 256] = h[(size_t)b * DD + tid + 256];
    swf[tid] = wf[tid];
    swf[tid + 256] = wf[tid + 256];
    __syncthreads();

    for (int a = tid; a < AD; a += 256) {
        float acc = bd[a];
        for (int k = 0; k < DD; k++) acc += shh[k] * Wd[(size_t)k * AD + a];
        sa2[a] = acc;
    }
    __syncthreads();

    // e[p]: one wave per p, float4 coalesced reads + shuffle reduce
    int w = tid >> 6, lane = tid & 63;
    float bf0 = bfv[0];
    for (int p = w; p < P; p += 4) {
        const float* row = att1 + ((size_t)b * P + p) * AD + lane * 8;
        float4 u0 = *(const float4*)row;
        float4 u1 = *(const float4*)(row + 4);
        float4 s0 = *(const float4*)&sa2[lane * 8];
        float4 s1 = *(const float4*)&sa2[lane * 8 + 4];
        float4 w0 = *(const float4*)&swf[lane * 8];
        float4 w1 = *(const float4*)&swf[lane * 8 + 4];
        float acc = fmaxf(u0.x + s0.x, 0.f) * w0.x + fmaxf(u0.y + s0.y, 0.f) * w0.y +
                    fmaxf(u0.z + s0.z, 0.f) * w0.z + fmaxf(u0.w + s0.w, 0.f) * w0.w +
                    fmaxf(u1.x + s1.x, 0.f) * w1.x + fmaxf(u1.y + s1.y, 0.f) * w1.y +
                    fmaxf(u1.z + s1.z, 0.f) * w1.z + fmaxf(u1.w + s1.w, 0.f) * w1.w;
#pragma unroll
        for (int m = 32; m >= 1; m >>= 1) acc += __shfl_xor(acc, m, 64);
        if (lane == 0) se[p] = acc + bf0;
    }
    __syncthreads();

    red[tid] = (tid < P) ? se[tid] : -1e30f;
    __syncthreads();
    for (int s = 128; s > 0; s >>= 1) {
        if (tid < s) red[tid] = fmaxf(red[tid], red[tid + s]);
        __syncthreads();
    }
    float mx = red[0];
    __syncthreads();
    float ex = (tid < P) ? expf(se[tid] - mx) : 0.f;
    red[tid] = ex;
    __syncthreads();
    for (int s = 128; s > 0; s >>= 1) {
        if (tid < s) red[tid] += red[tid + s];
        __syncthreads();
    }
    float inv = 1.0f / red[0];
    if (tid < P) {
        float a = ex * inv;
        alpha[(size_t)b * P + tid] = a;
        float m = (dlen[b] > t1) ? 1.f : 0.f;
        out[AOFF + ((size_t)b * TD + t1) * P + tid] = a * m;
    }
}

// ---------------------------------------------------------------------------
// S_B: awe + fbeta-gate + xg, writing K-major xT[300+d][b]; chunk 8 gathers emb_t
// ---------------------------------------------------------------------------
__global__ __launch_bounds__(256) void k_awexg(const float* __restrict__ eo,
                                               const int* __restrict__ sidx,
                                               const float* __restrict__ alpha,
                                               const float* __restrict__ hcur,
                                               const float* __restrict__ Wfb,
                                               const float* __restrict__ bfb,
                                               const float* __restrict__ emb,
                                               const int* __restrict__ caps_s,
                                               float* __restrict__ xT, int t) {
    int b = blockIdx.y, ch = blockIdx.x, tid = threadIdx.x;
    if (ch == 8) {
        if (tid < E) {
            int cap = caps_s[b * T + t];
            xT[(size_t)tid * B + b] = emb[(size_t)cap * E + tid];
        }
        return;
    }
    __shared__ float sal[P];
    __shared__ float shh[DD];
    if (tid < P) sal[tid] = alpha[(size_t)b * P + tid];
    shh[tid] = hcur[(size_t)b * DD + tid];
    shh[tid + 256] = hcur[(size_t)b * DD + tid + 256];
    __syncthreads();
    int d = ch * 256 + tid;
    const float* base = eo + ((size_t)sidx[b] * P) * ED + d;
    float aw = 0.f;
    for (int p = 0; p < P; p++) aw += base[(size_t)p * ED] * sal[p];
    float fb = bfb[d];
    for (int k = 0; k < DD; k++) fb += shh[k] * Wfb[(size_t)k * ED + d];
    xT[(size_t)(E + d) * B + b] = sigm(fb) * aw;
}

// ---------------------------------------------------------------------------
// S_C: gates partial GEMM.  grid 256 = 8 K-splits x 32 N-tiles(64 cols).
//      X read K-major from xT via L1-broadcast float4; W staged in LDS.
// ---------------------------------------------------------------------------
__global__ __launch_bounds__(256) void k_gates(const float* __restrict__ xT,
                                               const float* __restrict__ Wih,
                                               const float* __restrict__ Whh,
                                               float* __restrict__ part) {
    int bx = blockIdx.x;
    int ks = bx >> 5, nb = bx & 31;
    int n0 = nb * 64;
    int tid = threadIdx.x;
    int tb = tid & 15, tn = tid >> 4;
    __shared__ float sW[16][68];
    float acc[4][4] = {};
    int kbase = ks * KPER;

    for (int tile = 0; tile < 23; tile++) {
        int k0 = kbase + tile * 16;
        {
            int kk = tid >> 4, q = tid & 15;
            int kg = k0 + kk;
            float4 wv = make_float4(0.f, 0.f, 0.f, 0.f);
            if (kg < KX) wv = *(const float4*)&Wih[(size_t)kg * NG + n0 + q * 4];
            else if (kg < KTOT) wv = *(const float4*)&Whh[(size_t)(kg - KX) * NG + n0 + q * 4];
            *(float4*)&sW[kk][q * 4] = wv;
        }
        __syncthreads();
#pragma unroll
        for (int kk = 0; kk < 16; kk++) {
            int kg = k0 + kk;
            float4 xv = make_float4(0.f, 0.f, 0.f, 0.f);
            if (kg < KTOT) xv = *(const float4*)&xT[(size_t)kg * B + tb * 4];
            float4 wv = *(const float4*)&sW[kk][tn * 4];
            acc[0][0] += xv.x * wv.x; acc[0][1] += xv.x * wv.y; acc[0][2] += xv.x * wv.z; acc[0][3] += xv.x * wv.w;
            acc[1][0] += xv.y * wv.x; acc[1][1] += xv.y * wv.y; acc[1][2] += xv.y * wv.z; acc[1][3] += xv.y * wv.w;
            acc[2][0] += xv.z * wv.x; acc[2][1] += xv.z * wv.y; acc[2][2] += xv.z * wv.z; acc[2][3] += xv.z * wv.w;
            acc[3][0] += xv.w * wv.x; acc[3][1] += xv.w * wv.y; acc[3][2] += xv.w * wv.z; acc[3][3] += xv.w * wv.w;
        }
        __syncthreads();
    }
    float* pr = part + (size_t)ks * B * NG;
#pragma unroll
    for (int i = 0; i < 4; i++) {
        int b = tb * 4 + i;
        float4 o = make_float4(acc[i][0], acc[i][1], acc[i][2], acc[i][3]);
        *(float4*)&pr[(size_t)b * NG + n0 + tn * 4] = o;
    }
}

// ---------------------------------------------------------------------------
// S_D: reduce K-split partials + biases, LSTM cell, mask blend, write hT into xT
// ---------------------------------------------------------------------------
__global__ __launch_bounds__(256) void k_cell(const float* __restrict__ part,
                                              const float* __restrict__ bih,
                                              const float* __restrict__ bhh,
                                              const float* __restrict__ hc,
                                              const float* __restrict__ cc,
                                              const int* __restrict__ dlen,
                                              float* __restrict__ hn,
                                              float* __restrict__ cn,
                                              float* __restrict__ xT, int t) {
    int idx = blockIdx.x * 256 + threadIdx.x;  // B*DD
    int b = idx >> 9, j = idx & 511;
    float gi = bih[j] + bhh[j];
    float gf = bih[DD + j] + bhh[DD + j];
    float gg = bih[2 * DD + j] + bhh[2 * DD + j];
    float go = bih[3 * DD + j] + bhh[3 * DD + j];
#pragma unroll
    for (int s = 0; s < KSPLIT; s++) {
        const float* pr = part + ((size_t)s * B + b) * NG;
        gi += pr[j];
        gf += pr[DD + j];
        gg += pr[2 * DD + j];
        go += pr[3 * DD + j];
    }
    float cold = cc[idx], hold = hc[idx];
    float cnew = sigm(gf) * cold + sigm(gi) * tanhf(gg);
    float hnew = sigm(go) * tanhf(cnew);
    bool m = dlen[b] > t;
    float h2 = m ? hnew : hold;
    float c2 = m ? cnew : cold;
    hn[idx] = h2;
    cn[idx] = c2;
    xT[(size_t)(KX + j) * B + b] = h2;
}

// ---------------------------------------------------------------------------
extern "C" void kernel_launch(void* const* d_in, const int* in_sizes, int n_in,
                              void* d_out, int out_size, void* d_ws, size_t ws_size,
                              hipStream_t stream) {
    const float* eo    = (const float*)d_in[0];
    const int*   caps  = (const int*)d_in[1];
    const int*   lens  = (const int*)d_in[2];
    const float* emb   = (const float*)d_in[3];
    const float* Wea   = (const float*)d_in[4];
    const float* bea   = (const float*)d_in[5];
    const float* Wda   = (const float*)d_in[6];
    const float* bda   = (const float*)d_in[7];
    const float* wfull = (const float*)d_in[8];
    const float* bfull = (const float*)d_in[9];
    const float* Wih_  = (const float*)d_in[10];
    const float* bih_  = (const float*)d_in[11];
    const float* Wic   = (const float*)d_in[12];
    const float* bic   = (const float*)d_in[13];
    const float* Wfb   = (const float*)d_in[14];
    const float* bfb   = (const float*)d_in[15];
    const float* Wih   = (const float*)d_in[16];
    const float* bih   = (const float*)d_in[17];
    const float* Whh   = (const float*)d_in[18];
    const float* bhh   = (const float*)d_in[19];
    const float* Wfc   = (const float*)d_in[20];
    const float* bfc   = (const float*)d_in[21];
    float* out = (float*)d_out;

    char* w = (char*)d_ws;
    auto carve = [&](size_t bytes) -> void* {
        void* p = (void*)w;
        w += (bytes + 255) & ~(size_t)255;
        return p;
    };
    int* sidx     = (int*)carve(B * 4);
    int* dlen     = (int*)carve(B * 4);
    int* caps_s   = (int*)carve((size_t)B * T * 4);
    float* mean_eo = (float*)carve((size_t)B * ED * 4);
    float* hb0    = (float*)carve((size_t)B * DD * 4);
    float* hb1    = (float*)carve((size_t)B * DD * 4);
    float* cb0    = (float*)carve((size_t)B * DD * 4);
    float* cb1    = (float*)carve((size_t)B * DD * 4);
    float* att1   = (float*)carve((size_t)B * P * AD * 4);
    float* alpha  = (float*)carve((size_t)B * P * 4);
    float* xT     = (float*)carve((size_t)(KSPLIT * KPER) * B * 4);
    float* part   = (float*)carve((size_t)KSPLIT * B * NG * 4);
    float* hb[2] = {hb0, hb1};
    float* cb[2] = {cb0, cb1};

    k_sort<<<1, 64, 0, stream>>>(lens, caps, sidx, dlen, caps_s, out);
    k_mean<<<dim3(ED / 256, B), 256, 0, stream>>>(eo, sidx, mean_eo);
    k_init<<<(B * DD) / 256, 256, 0, stream>>>(mean_eo, Wih_, bih_, Wic, bic, hb[0], cb[0], xT);
    k_att1<<<dim3((B * P) / 64, AD / 64), 256, 0, stream>>>(eo, Wea, bea, sidx, att1);
    // alpha for t=0 (att-part only)
    k_attpred<<<64, 256, 0, stream>>>(hb[0], att1, Wda, bda, wfull, bfull, Wfc, bfc,
                                      dlen, alpha, out, -1, 0);

    for (int t = 0; t < TD; t++) {
        float* hc = hb[t & 1];
        float* cc = cb[t & 1];
        float* hn = hb[(t + 1) & 1];
        float* cn = cb[(t + 1) & 1];
        k_awexg<<<dim3(9, B), 256, 0, stream>>>(eo, sidx, alpha, hc, Wfb, bfb, emb, caps_s, xT, t);
        k_gates<<<256, 256, 0, stream>>>(xT, Wih, Whh, part);
        k_cell<<<(B * DD) / 256, 256, 0, stream>>>(part, bih, bhh, hc, cc, dlen, hn, cn, xT, t);
        k_attpred<<<314, 256, 0, stream>>>(hn, att1, Wda, bda, wfull, bfull, Wfc, bfc,
                                           dlen, alpha, out, t, 250);
    }
}

// Round 3
// 19473.628 us; speedup vs baseline: 2.9256x; 1.0585x over previous
//
#include <hip/hip_runtime.h>
#include <stddef.h>
#include <math.h>

static constexpr int B = 64, P = 196, ED = 2048, AD = 512, DD = 512, E = 300, V = 1000, T = 96, TD = 95;
static constexpr int KX = E + ED;      // 2348
static constexpr int KTOT = KX + DD;   // 2860
static constexpr int KSPLIT = 8;
static constexpr int KPER = 368;       // 23 tiles of 16; 8*368 = 2944 >= 2860
static constexpr int NG = 4 * DD;      // 2048

// d_out layout (all float32): predictions (B,TD,V), caps (B,T), decode_lengths (B),
// alphas (B,TD,P), sort_ind (B)
static constexpr size_t POFF   = 0;
static constexpr size_t CAPOFF = (size_t)B * TD * V;
static constexpr size_t DLOFF  = CAPOFF + (size_t)B * T;
static constexpr size_t AOFF   = DLOFF + B;
static constexpr size_t SOFF   = AOFF + (size_t)B * TD * P;

__device__ __forceinline__ float sigm(float x) { return 1.0f / (1.0f + expf(-x)); }

// ---------------------------------------------------------------------------
// K0: stable descending sort by length + gather caps + write int-ish outputs
// ---------------------------------------------------------------------------
__global__ __launch_bounds__(64) void k_sort(const int* __restrict__ lens,
                                             const int* __restrict__ caps_in,
                                             int* __restrict__ sidx,
                                             int* __restrict__ dlen,
                                             int* __restrict__ caps_s,
                                             float* __restrict__ out) {
    __shared__ int sl[B];
    __shared__ int ss[B];
    int i = threadIdx.x;
    sl[i] = lens[i];
    __syncthreads();
    int li = sl[i];
    int r = 0;
    for (int j = 0; j < B; j++) {
        int lj = sl[j];
        r += (lj > li) || (lj == li && j < i);
    }
    ss[r] = i;
    sidx[r] = i;
    dlen[r] = li - 1;
    out[DLOFF + r] = (float)(li - 1);
    out[SOFF + r] = (float)i;
    __syncthreads();
    for (int idx = i; idx < B * T; idx += B) {
        int b = idx / T, tt = idx % T;
        int v = caps_in[ss[b] * T + tt];
        caps_s[idx] = v;
        out[CAPOFF + idx] = (float)v;
    }
}

// ---------------------------------------------------------------------------
// K1: mean over P of sorted encoder_out -> mean_eo (B, ED)
// ---------------------------------------------------------------------------
__global__ __launch_bounds__(256) void k_mean(const float* __restrict__ eo,
                                              const int* __restrict__ sidx,
                                              float* __restrict__ mean_eo) {
    int b = blockIdx.y;
    int d = blockIdx.x * 256 + threadIdx.x;
    const float* base = eo + ((size_t)sidx[b] * P) * ED + d;
    float s = 0.f;
    for (int p = 0; p < P; p++) s += base[(size_t)p * ED];
    mean_eo[(size_t)b * ED + d] = s * (1.0f / (float)P);
}

// ---------------------------------------------------------------------------
// K2: h0/c0 init; seeds the h-rows of xT (K-major x buffer)
// ---------------------------------------------------------------------------
__global__ __launch_bounds__(256) void k_init(const float* __restrict__ mean_eo,
                                              const float* __restrict__ Wh, const float* __restrict__ bh,
                                              const float* __restrict__ Wc, const float* __restrict__ bc,
                                              float* __restrict__ h0, float* __restrict__ c0,
                                              float* __restrict__ xT) {
    int idx = blockIdx.x * 256 + threadIdx.x;  // B*DD
    int b = idx >> 9, j = idx & 511;
    const float* m = mean_eo + (size_t)b * ED;
    float ah = bh[j], ac = bc[j];
    for (int k = 0; k < ED; k++) {
        float mv = m[k];
        ah += mv * Wh[(size_t)k * DD + j];
        ac += mv * Wc[(size_t)k * DD + j];
    }
    h0[idx] = ah;
    c0[idx] = ac;
    xT[(size_t)(KX + j) * B + b] = ah;
}

// ---------------------------------------------------------------------------
// K3: att1[m,n] = eo_sorted[m,:] @ W_enc_att[:,n] + b   (row-major, B*P x AD)
// ---------------------------------------------------------------------------
__global__ __launch_bounds__(256) void k_att1(const float* __restrict__ eo,
                                              const float* __restrict__ W,
                                              const float* __restrict__ bias,
                                              const int* __restrict__ sidx,
                                              float* __restrict__ att1) {
    int m0 = blockIdx.x * 64, n0 = blockIdx.y * 64;
    __shared__ float sA[16][68];
    __shared__ float sB[16][68];
    int tid = threadIdx.x;
    int tx = tid & 15, ty = tid >> 4;
    float acc[4][4] = {};

    int la_m = tid >> 2;
    int la_k = (tid & 3) * 4;
    int lb_k = tid >> 4;
    int lb_n = (tid & 15) * 4;

    int mA = m0 + la_m;
    int bA = mA / P, pA = mA % P;
    const float* arow = eo + ((size_t)sidx[bA] * P + pA) * ED;

    for (int k0 = 0; k0 < ED; k0 += 16) {
        float4 av = *(const float4*)(arow + k0 + la_k);
        sA[la_k + 0][la_m] = av.x;
        sA[la_k + 1][la_m] = av.y;
        sA[la_k + 2][la_m] = av.z;
        sA[la_k + 3][la_m] = av.w;
        float4 bv = *(const float4*)(W + (size_t)(k0 + lb_k) * AD + n0 + lb_n);
        *(float4*)&sB[lb_k][lb_n] = bv;
        __syncthreads();
#pragma unroll
        for (int kk = 0; kk < 16; kk++) {
            float4 a4 = *(const float4*)&sA[kk][ty * 4];
            float4 b4 = *(const float4*)&sB[kk][tx * 4];
            float av_[4] = {a4.x, a4.y, a4.z, a4.w};
            float bv_[4] = {b4.x, b4.y, b4.z, b4.w};
#pragma unroll
            for (int i = 0; i < 4; i++)
#pragma unroll
                for (int j = 0; j < 4; j++) acc[i][j] += av_[i] * bv_[j];
        }
        __syncthreads();
    }
#pragma unroll
    for (int i = 0; i < 4; i++) {
        int m = m0 + ty * 4 + i;
        int n = n0 + tx * 4;
        float4 o;
        o.x = acc[i][0] + bias[n + 0];
        o.y = acc[i][1] + bias[n + 1];
        o.z = acc[i][2] + bias[n + 2];
        o.w = acc[i][3] + bias[n + 3];
        *(float4*)(att1 + (size_t)m * AD + n) = o;
    }
}

// ---------------------------------------------------------------------------
// kA1: blocks [0,80): B-tiled small GEMMs off hprev — each weight read ONCE.
//        n in [0,512):   att2[b][n]  = hprev@Wda + bda          (no act)
//        n in [512,2560): fg[b][n-512] = sigm(hprev@Wfb + bfb)
//      blocks [80,85): gather emb(t) into xT rows [0,300).
// ---------------------------------------------------------------------------
__global__ __launch_bounds__(256) void kA1(const float* __restrict__ hprev,
                                           const float* __restrict__ Wda, const float* __restrict__ bda,
                                           const float* __restrict__ Wfb, const float* __restrict__ bfb,
                                           const float* __restrict__ emb,
                                           const int* __restrict__ caps_s,
                                           float* __restrict__ att2g,
                                           float* __restrict__ fg,
                                           float* __restrict__ xT, int t) {
    int bx = blockIdx.x;
    int tid = threadIdx.x;
    if (bx >= 80) {
        // emb gather: 60 k-rows per block
        int k0 = (bx - 80) * 60;
        for (int l = tid; l < 60 * 64; l += 256) {
            int r = l >> 6, b = l & 63;
            int k = k0 + r;
            int cap = caps_s[b * T + t];
            xT[(size_t)k * B + b] = emb[(size_t)cap * E + k];
        }
        return;
    }
    int n0 = bx * 32;
    bool is_att = (n0 < AD);
    __shared__ float sH[16][68];
    __shared__ float sW[16][36];
    float acc[4][2] = {};
    int tb = tid & 15, tn = tid >> 4;

    for (int k0 = 0; k0 < DD; k0 += 16) {
        {
            int b = tid >> 2, q = tid & 3;
            float4 hv = *(const float4*)(hprev + (size_t)b * DD + k0 + q * 4);
            sH[q * 4 + 0][b] = hv.x;
            sH[q * 4 + 1][b] = hv.y;
            sH[q * 4 + 2][b] = hv.z;
            sH[q * 4 + 3][b] = hv.w;
        }
        if (tid < 128) {
            int kk = tid >> 3, nn = (tid & 7) * 4;
            float4 wv;
            if (is_att) wv = *(const float4*)(Wda + (size_t)(k0 + kk) * AD + n0 + nn);
            else        wv = *(const float4*)(Wfb + (size_t)(k0 + kk) * ED + (n0 - AD) + nn);
            *(float4*)&sW[kk][nn] = wv;
        }
        __syncthreads();
#pragma unroll
        for (int kk = 0; kk < 16; kk++) {
            float4 hv = *(const float4*)&sH[kk][tb * 4];
            float w0 = sW[kk][tn * 2 + 0];
            float w1 = sW[kk][tn * 2 + 1];
            acc[0][0] += hv.x * w0; acc[0][1] += hv.x * w1;
            acc[1][0] += hv.y * w0; acc[1][1] += hv.y * w1;
            acc[2][0] += hv.z * w0; acc[2][1] += hv.z * w1;
            acc[3][0] += hv.w * w0; acc[3][1] += hv.w * w1;
        }
        __syncthreads();
    }
#pragma unroll
    for (int i = 0; i < 4; i++)
#pragma unroll
        for (int j = 0; j < 2; j++) {
            int b = tb * 4 + i;
            int n = n0 + tn * 2 + j;
            float v = acc[i][j];
            if (is_att) att2g[(size_t)b * AD + n] = v + bda[n];
            else {
                int d = n - AD;
                fg[(size_t)b * ED + d] = sigm(v + bfb[d]);
            }
        }
}

// ---------------------------------------------------------------------------
// kA2: per-b softmax: e = relu(att1+att2)·wf + bf ; alpha (ws) + masked out
// ---------------------------------------------------------------------------
__global__ __launch_bounds__(256) void kA2(const float* __restrict__ att2g,
                                           const float* __restrict__ att1,
                                           const float* __restrict__ wf,
                                           const float* __restrict__ bfv,
                                           const int* __restrict__ dlen,
                                           float* __restrict__ alpha,
                                           float* __restrict__ out, int t) {
    int b = blockIdx.x;
    int tid = threadIdx.x;
    __shared__ float sa2[AD];
    __shared__ float swf[AD];
    __shared__ float se[P];
    __shared__ float red[256];

    sa2[tid] = att2g[(size_t)b * AD + tid];
    sa2[tid + 256] = att2g[(size_t)b * AD + tid + 256];
    swf[tid] = wf[tid];
    swf[tid + 256] = wf[tid + 256];
    __syncthreads();

    int w = tid >> 6, lane = tid & 63;
    float bf0 = bfv[0];
    for (int p = w; p < P; p += 4) {
        const float* row = att1 + ((size_t)b * P + p) * AD + lane * 8;
        float4 u0 = *(const float4*)row;
        float4 u1 = *(const float4*)(row + 4);
        float4 s0 = *(const float4*)&sa2[lane * 8];
        float4 s1 = *(const float4*)&sa2[lane * 8 + 4];
        float4 w0 = *(const float4*)&swf[lane * 8];
        float4 w1 = *(const float4*)&swf[lane * 8 + 4];
        float acc = fmaxf(u0.x + s0.x, 0.f) * w0.x + fmaxf(u0.y + s0.y, 0.f) * w0.y +
                    fmaxf(u0.z + s0.z, 0.f) * w0.z + fmaxf(u0.w + s0.w, 0.f) * w0.w +
                    fmaxf(u1.x + s1.x, 0.f) * w1.x + fmaxf(u1.y + s1.y, 0.f) * w1.y +
                    fmaxf(u1.z + s1.z, 0.f) * w1.z + fmaxf(u1.w + s1.w, 0.f) * w1.w;
#pragma unroll
        for (int m = 32; m >= 1; m >>= 1) acc += __shfl_xor(acc, m, 64);
        if (lane == 0) se[p] = acc + bf0;
    }
    __syncthreads();

    red[tid] = (tid < P) ? se[tid] : -1e30f;
    __syncthreads();
    for (int s = 128; s > 0; s >>= 1) {
        if (tid < s) red[tid] = fmaxf(red[tid], red[tid + s]);
        __syncthreads();
    }
    float mx = red[0];
    __syncthreads();
    float ex = (tid < P) ? expf(se[tid] - mx) : 0.f;
    red[tid] = ex;
    __syncthreads();
    for (int s = 128; s > 0; s >>= 1) {
        if (tid < s) red[tid] += red[tid + s];
        __syncthreads();
    }
    float inv = 1.0f / red[0];
    if (tid < P) {
        float a = ex * inv;
        alpha[(size_t)b * P + tid] = a;
        float m = (dlen[b] > t) ? 1.f : 0.f;
        out[AOFF + ((size_t)b * TD + t) * P + tid] = a * m;
    }
}

// ---------------------------------------------------------------------------
// kB: awe + xg = fg*awe, write K-major xT rows [300, 2348)
// ---------------------------------------------------------------------------
__global__ __launch_bounds__(256) void kB(const float* __restrict__ eo,
                                          const int* __restrict__ sidx,
                                          const float* __restrict__ alpha,
                                          const float* __restrict__ fg,
                                          float* __restrict__ xT) {
    int b = blockIdx.y, ch = blockIdx.x, tid = threadIdx.x;
    __shared__ float sal[P];
    if (tid < P) sal[tid] = alpha[(size_t)b * P + tid];
    __syncthreads();
    int d = ch * 256 + tid;
    const float* base = eo + ((size_t)sidx[b] * P) * ED + d;
    float aw = 0.f;
    for (int p = 0; p < P; p++) aw += base[(size_t)p * ED] * sal[p];
    xT[(size_t)(E + d) * B + b] = fg[(size_t)b * ED + d] * aw;
}

// ---------------------------------------------------------------------------
// kC: gates partial GEMM. grid 512 = 8 K-splits x 64 N-tiles(32 cols).
// ---------------------------------------------------------------------------
__global__ __launch_bounds__(256) void kC(const float* __restrict__ xT,
                                          const float* __restrict__ Wih,
                                          const float* __restrict__ Whh,
                                          float* __restrict__ part) {
    int bx = blockIdx.x;
    int ks = bx >> 6, nb = bx & 63;
    int n0 = nb * 32;
    int tid = threadIdx.x;
    int tb = tid & 15, tn = tid >> 4;
    __shared__ float sW[16][36];
    float acc[4][2] = {};
    int kbase = ks * KPER;

    for (int tile = 0; tile < 23; tile++) {
        int k0 = kbase + tile * 16;
        if (tid < 128) {
            int kk = tid >> 3, nn = (tid & 7) * 4;
            int kg = k0 + kk;
            float4 wv = make_float4(0.f, 0.f, 0.f, 0.f);
            if (kg < KX) wv = *(const float4*)&Wih[(size_t)kg * NG + n0 + nn];
            else if (kg < KTOT) wv = *(const float4*)&Whh[(size_t)(kg - KX) * NG + n0 + nn];
            *(float4*)&sW[kk][nn] = wv;
        }
        __syncthreads();
#pragma unroll
        for (int kk = 0; kk < 16; kk++) {
            int kg = k0 + kk;
            float4 xv = make_float4(0.f, 0.f, 0.f, 0.f);
            if (kg < KTOT) xv = *(const float4*)&xT[(size_t)kg * B + tb * 4];
            float w0 = sW[kk][tn * 2 + 0];
            float w1 = sW[kk][tn * 2 + 1];
            acc[0][0] += xv.x * w0; acc[0][1] += xv.x * w1;
            acc[1][0] += xv.y * w0; acc[1][1] += xv.y * w1;
            acc[2][0] += xv.z * w0; acc[2][1] += xv.z * w1;
            acc[3][0] += xv.w * w0; acc[3][1] += xv.w * w1;
        }
        __syncthreads();
    }
    float* pr = part + (size_t)ks * B * NG;
#pragma unroll
    for (int i = 0; i < 4; i++)
#pragma unroll
        for (int j = 0; j < 2; j++) {
            int b = tb * 4 + i, n = n0 + tn * 2 + j;
            pr[(size_t)b * NG + n] = acc[i][j];
        }
}

// ---------------------------------------------------------------------------
// kD: reduce partials + biases, LSTM cell, mask blend; write hseq[t] + xT h-rows
// ---------------------------------------------------------------------------
__global__ __launch_bounds__(256) void kD(const float* __restrict__ part,
                                          const float* __restrict__ bih,
                                          const float* __restrict__ bhh,
                                          const float* __restrict__ hprev,
                                          const float* __restrict__ cc,
                                          const int* __restrict__ dlen,
                                          float* __restrict__ hseq_t,
                                          float* __restrict__ cn,
                                          float* __restrict__ xT, int t) {
    int idx = blockIdx.x * 256 + threadIdx.x;  // B*DD
    int b = idx >> 9, j = idx & 511;
    float gi = bih[j] + bhh[j];
    float gf = bih[DD + j] + bhh[DD + j];
    float gg = bih[2 * DD + j] + bhh[2 * DD + j];
    float go = bih[3 * DD + j] + bhh[3 * DD + j];
#pragma unroll
    for (int s = 0; s < KSPLIT; s++) {
        const float* pr = part + ((size_t)s * B + b) * NG;
        gi += pr[j];
        gf += pr[DD + j];
        gg += pr[2 * DD + j];
        go += pr[3 * DD + j];
    }
    float cold = cc[idx], hold = hprev[idx];
    float cnew = sigm(gf) * cold + sigm(gi) * tanhf(gg);
    float hnew = sigm(go) * tanhf(cnew);
    bool m = dlen[b] > t;
    float h2 = m ? hnew : hold;
    float c2 = m ? cnew : cold;
    hseq_t[idx] = h2;
    cn[idx] = c2;
    xT[(size_t)(KX + j) * B + b] = h2;
}

// ---------------------------------------------------------------------------
// K4: batched preds GEMM: out[b,t,v] = mask * (hseq[t,b,:]@Wfc + bfc)
//     grid (95 t-tiles, 16 n-tiles of 64; N=1000 tail-guarded)
// ---------------------------------------------------------------------------
__global__ __launch_bounds__(256) void k_predsall(const float* __restrict__ hseq,
                                                  const float* __restrict__ Wfc,
                                                  const float* __restrict__ bfc,
                                                  const int* __restrict__ dlen,
                                                  float* __restrict__ out) {
    int t = blockIdx.x;
    int n0 = blockIdx.y * 64;
    int tid = threadIdx.x;
    int tx = tid & 15, ty = tid >> 4;
    __shared__ float sA[16][68];
    __shared__ float sB[16][68];
    float acc[4][4] = {};
    const float* A = hseq + (size_t)t * B * DD;

    for (int k0 = 0; k0 < DD; k0 += 16) {
        {
            int b = tid >> 2, q = tid & 3;
            float4 hv = *(const float4*)(A + (size_t)b * DD + k0 + q * 4);
            sA[q * 4 + 0][b] = hv.x;
            sA[q * 4 + 1][b] = hv.y;
            sA[q * 4 + 2][b] = hv.z;
            sA[q * 4 + 3][b] = hv.w;
        }
        {
            int kk = tid >> 4, nn = (tid & 15) * 4;
            int c = n0 + nn;
            const float* wrow = Wfc + (size_t)(k0 + kk) * V;
            float4 wv;
            if (c + 3 < V) wv = *(const float4*)(wrow + c);
            else {
                wv.x = (c + 0 < V) ? wrow[c + 0] : 0.f;
                wv.y = (c + 1 < V) ? wrow[c + 1] : 0.f;
                wv.z = (c + 2 < V) ? wrow[c + 2] : 0.f;
                wv.w = (c + 3 < V) ? wrow[c + 3] : 0.f;
            }
            *(float4*)&sB[kk][nn] = wv;
        }
        __syncthreads();
#pragma unroll
        for (int kk = 0; kk < 16; kk++) {
            float4 a4 = *(const float4*)&sA[kk][ty * 4];
            float4 b4 = *(const float4*)&sB[kk][tx * 4];
            float av_[4] = {a4.x, a4.y, a4.z, a4.w};
            float bv_[4] = {b4.x, b4.y, b4.z, b4.w};
#pragma unroll
            for (int i = 0; i < 4; i++)
#pragma unroll
                for (int j = 0; j < 4; j++) acc[i][j] += av_[i] * bv_[j];
        }
        __syncthreads();
    }
#pragma unroll
    for (int i = 0; i < 4; i++) {
        int b = ty * 4 + i;
        bool m = dlen[b] > t;
#pragma unroll
        for (int j = 0; j < 4; j++) {
            int n = n0 + tx * 4 + j;
            if (n < V)
                out[POFF + ((size_t)b * TD + t) * V + n] = m ? (acc[i][j] + bfc[n]) : 0.f;
        }
    }
}

// ---------------------------------------------------------------------------
extern "C" void kernel_launch(void* const* d_in, const int* in_sizes, int n_in,
                              void* d_out, int out_size, void* d_ws, size_t ws_size,
                              hipStream_t stream) {
    const float* eo    = (const float*)d_in[0];
    const int*   caps  = (const int*)d_in[1];
    const int*   lens  = (const int*)d_in[2];
    const float* emb   = (const float*)d_in[3];
    const float* Wea   = (const float*)d_in[4];
    const float* bea   = (const float*)d_in[5];
    const float* Wda   = (const float*)d_in[6];
    const float* bda   = (const float*)d_in[7];
    const float* wfull = (const float*)d_in[8];
    const float* bfull = (const float*)d_in[9];
    const float* Wih_  = (const float*)d_in[10];
    const float* bih_  = (const float*)d_in[11];
    const float* Wic   = (const float*)d_in[12];
    const float* bic   = (const float*)d_in[13];
    const float* Wfb   = (const float*)d_in[14];
    const float* bfb   = (const float*)d_in[15];
    const float* Wih   = (const float*)d_in[16];
    const float* bih   = (const float*)d_in[17];
    const float* Whh   = (const float*)d_in[18];
    const float* bhh   = (const float*)d_in[19];
    const float* Wfc   = (const float*)d_in[20];
    const float* bfc   = (const float*)d_in[21];
    float* out = (float*)d_out;

    char* w = (char*)d_ws;
    auto carve = [&](size_t bytes) -> void* {
        void* p = (void*)w;
        w += (bytes + 255) & ~(size_t)255;
        return p;
    };
    int* sidx      = (int*)carve(B * 4);
    int* dlen      = (int*)carve(B * 4);
    int* caps_s    = (int*)carve((size_t)B * T * 4);
    float* mean_eo = (float*)carve((size_t)B * ED * 4);
    float* h0      = (float*)carve((size_t)B * DD * 4);
    float* cb0     = (float*)carve((size_t)B * DD * 4);
    float* cb1     = (float*)carve((size_t)B * DD * 4);
    float* att1    = (float*)carve((size_t)B * P * AD * 4);
    float* alphaW  = (float*)carve((size_t)B * P * 4);
    float* att2g   = (float*)carve((size_t)B * AD * 4);
    float* fg      = (float*)carve((size_t)B * ED * 4);
    float* xT      = (float*)carve((size_t)KTOT * B * 4);
    float* part    = (float*)carve((size_t)KSPLIT * B * NG * 4);
    float* hseq    = (float*)carve((size_t)TD * B * DD * 4);
    float* cb[2] = {cb0, cb1};

    k_sort<<<1, 64, 0, stream>>>(lens, caps, sidx, dlen, caps_s, out);
    k_mean<<<dim3(ED / 256, B), 256, 0, stream>>>(eo, sidx, mean_eo);
    k_init<<<(B * DD) / 256, 256, 0, stream>>>(mean_eo, Wih_, bih_, Wic, bic, h0, cb0, xT);
    k_att1<<<dim3((B * P) / 64, AD / 64), 256, 0, stream>>>(eo, Wea, bea, sidx, att1);

    for (int t = 0; t < TD; t++) {
        const float* hprev = (t == 0) ? h0 : (hseq + (size_t)(t - 1) * B * DD);
        float* cc = cb[t & 1];
        float* cn = cb[(t + 1) & 1];
        kA1<<<85, 256, 0, stream>>>(hprev, Wda, bda, Wfb, bfb, emb, caps_s, att2g, fg, xT, t);
        kA2<<<64, 256, 0, stream>>>(att2g, att1, wfull, bfull, dlen, alphaW, out, t);
        kB<<<dim3(8, B), 256, 0, stream>>>(eo, sidx, alphaW, fg, xT);
        kC<<<512, 256, 0, stream>>>(xT, Wih, Whh, part);
        kD<<<(B * DD) / 256, 256, 0, stream>>>(part, bih, bhh, hprev, cc, dlen,
                                               hseq + (size_t)t * B * DD, cn, xT, t);
    }
    k_predsall<<<dim3(TD, 16), 256, 0, stream>>>(hseq, Wfc, bfc, dlen, out);
}